// Round 1
// baseline (327.031 us; speedup 1.0000x reference)
//
#include <hip/hip_runtime.h>

#define H 2048
#define E_EXP 64
#define T_TOTAL 16384
#define W_OFF 32768  // weights start after 16384*2 idx floats

// LDS index swizzle: conflict-free for all three access patterns
__device__ __forceinline__ int sw(int tok, int e) { return e ^ (tok & 31); }

__global__ __launch_bounds__(1024) void moe_gate_kernel(
    const float* __restrict__ x, const float* __restrict__ W,
    float* __restrict__ out, float* __restrict__ ws) {
  // part[hs][tok_lane][e] (swizzled last dim): 4*64*64*4B = 64 KiB
  __shared__ float part[4][64][64];

  const int tid = threadIdx.x;
  const int lane = tid & 63;
  // readfirstlane -> SGPR so W addressing is provably wave-uniform (s_load path)
  const int wv = __builtin_amdgcn_readfirstlane(tid >> 6);  // wave id 0..15
  const int eg = wv & 3;   // expert group: experts [eg*16, eg*16+16)
  const int hs = wv >> 2;  // H slice:      h in [hs*512, hs*512+512)
  const int tok = blockIdx.x * 64 + lane;

  const float* __restrict__ xrow = x + (size_t)tok * H + hs * 512;
  const float* __restrict__ wbase = W + (size_t)(eg * 16) * H + hs * 512;

  float acc[16];
#pragma unroll
  for (int i = 0; i < 16; ++i) acc[i] = 0.f;

  for (int h = 0; h < 512; h += 8) {
    float4 xa = *(const float4*)(xrow + h);
    float4 xb = *(const float4*)(xrow + h + 4);
#pragma unroll
    for (int i = 0; i < 16; ++i) {
      const float* wr = wbase + i * H + h;  // wave-uniform address
      float4 wa = *(const float4*)(wr);
      float4 wb = *(const float4*)(wr + 4);
      acc[i] += xa.x * wa.x + xa.y * wa.y + xa.z * wa.z + xa.w * wa.w +
                xb.x * wb.x + xb.y * wb.y + xb.z * wb.z + xb.w * wb.w;
    }
  }

#pragma unroll
  for (int i = 0; i < 16; ++i) part[hs][lane][sw(lane, eg * 16 + i)] = acc[i];
  __syncthreads();

  // reduce the 4 H-slices: 4096 (tok,e) pairs over 1024 threads
  for (int p = tid; p < 4096; p += 1024) {
    int tk = p >> 6, e = p & 63;
    int s = sw(tk, e);
    part[0][tk][s] = part[0][tk][s] + part[1][tk][s] + part[2][tk][s] + part[3][tk][s];
  }
  __syncthreads();

  if (wv == 0) {  // 64 lanes, one token each
    float l[64];
    float m1 = -3e38f, m2 = -3e38f;
    int i1 = 0, i2 = 0;
#pragma unroll
    for (int e = 0; e < 64; ++e) {
      float v = part[0][lane][sw(lane, e)];
      l[e] = v;
      // strict '>' ascending-e: ties keep lower index (matches jax.lax.top_k)
      if (v > m1) { m2 = m1; i2 = i1; m1 = v; i1 = e; }
      else if (v > m2) { m2 = v; i2 = e; }
    }
    float Z = 0.f;
#pragma unroll
    for (int e = 0; e < 64; ++e) {
      float s = __expf(l[e] - m1);
      l[e] = s;
      Z += s;
    }
    float invZ = 1.f / Z;
    float s1 = invZ;                       // exp(m1-m1)*invZ
    float s2 = __expf(m2 - m1) * invZ;
    float dn = 1.f / (s1 + s2 + 1e-20f);

    out[(size_t)tok * 2 + 0] = (float)i1;
    out[(size_t)tok * 2 + 1] = (float)i2;
    out[W_OFF + (size_t)tok * 2 + 0] = s1 * dn;
    out[W_OFF + (size_t)tok * 2 + 1] = s2 * dn;

    const int b = tok >> 12;  // 4096 tokens per batch row
    // top-2 counts for aux loss
    atomicAdd(&ws[256 + b * 64 + i1], 1.0f);
    atomicAdd(&ws[256 + b * 64 + i2], 1.0f);
    // per-expert softmax score sums: wave-reduce 64 tokens, 1 atomic per e
#pragma unroll
    for (int e = 0; e < 64; ++e) {
      float v = l[e] * invZ;
      v += __shfl_xor(v, 32, 64);
      v += __shfl_xor(v, 16, 64);
      v += __shfl_xor(v, 8, 64);
      v += __shfl_xor(v, 4, 64);
      v += __shfl_xor(v, 2, 64);
      v += __shfl_xor(v, 1, 64);
      if (lane == 0) atomicAdd(&ws[b * 64 + e], v);
    }
  }
}

__global__ void moe_gate_finalize(const float* __restrict__ ws,
                                  float* __restrict__ out) {
  const int tid = threadIdx.x;  // 256
  const int b = tid >> 6, e = tid & 63;
  // ce = count * E/(S*K) = count/128 ; expert_scores = score_sum/S
  float v = ws[256 + b * 64 + e] * (64.f / 8192.f) * (ws[b * 64 + e] / 4096.f);
  v += __shfl_xor(v, 32, 64);
  v += __shfl_xor(v, 16, 64);
  v += __shfl_xor(v, 8, 64);
  v += __shfl_xor(v, 4, 64);
  v += __shfl_xor(v, 2, 64);
  v += __shfl_xor(v, 1, 64);
  __shared__ float red[4];
  if ((tid & 63) == 0) red[tid >> 6] = v;
  __syncthreads();
  if (tid == 0) out[65536] = 0.1f * 0.25f * (red[0] + red[1] + red[2] + red[3]);
}

extern "C" void kernel_launch(void* const* d_in, const int* in_sizes, int n_in,
                              void* d_out, int out_size, void* d_ws, size_t ws_size,
                              hipStream_t stream) {
  const float* x = (const float*)d_in[0];
  const float* W = (const float*)d_in[1];
  float* out = (float*)d_out;
  float* ws = (float*)d_ws;
  hipMemsetAsync(d_ws, 0, 512 * sizeof(float), stream);  // counts + score sums
  moe_gate_kernel<<<256, 1024, 0, stream>>>(x, W, out, ws);
  moe_gate_finalize<<<1, 256, 0, stream>>>(ws, out);
}